// Round 7
// baseline (858.062 us; speedup 1.0000x reference)
//
#include <hip/hip_runtime.h>

// SimSiam: N=8192, D=256, H=128, fp32 in/out.
// Sim via split-fp32 bf16 MFMA: sim = Ah·Bh^T + Al·Bh^T + Ah·Bl^T.
// 256x256 tile, 8 waves (4x2 of 64x128), all four planes co-staged per K-tile
// (8 steps, 96 MFMA/wave/step), dbuf-2, one block/CU. Planes in MFMA-tile
// format: granule16B(panel,kt,kq,m) = ((panel*8+kt)*4+kq)*128+m (panel=128 rows).
// Loss = mean(diag(sim)) from diagonal blocks' accumulators.

static constexpr int N = 8192;
static constexpr int D = 256;
static constexpr int H = 128;

typedef __attribute__((ext_vector_type(8))) short s16x8;
typedef __attribute__((ext_vector_type(4))) float fp32x4;
typedef unsigned long long ull;

__device__ __forceinline__ unsigned f2ord(float f) {
    unsigned u = __float_as_uint(f);
    return (u & 0x80000000u) ? ~u : (u | 0x80000000u);
}
__device__ __forceinline__ ull umax64(ull a, ull b) { return a > b ? a : b; }
__device__ __forceinline__ unsigned short bf16_rtne(float f) {
    unsigned u = __float_as_uint(f);
    unsigned r = 0x7FFFu + ((u >> 16) & 1u);
    return (unsigned short)((u + r) >> 16);
}
__device__ __forceinline__ float bf_f(unsigned short h) {
    return __uint_as_float((unsigned)h << 16);
}
__device__ __forceinline__ void split_store(float f, unsigned short* h, unsigned short* l) {
    unsigned short hb = bf16_rtne(f);
    *h = hb;
    *l = bf16_rtne(f - bf_f(hb));
}
__device__ __forceinline__ void gload16(const unsigned short* g, void* lds) {
    __builtin_amdgcn_global_load_lds(
        (const __attribute__((address_space(1))) unsigned int*)g,
        (__attribute__((address_space(3))) unsigned int*)lds, 16, 0, 0);
}
// tile-format granule index (in ushort units)
__device__ __forceinline__ size_t gidx(int panel, int kt, int kq, int m) {
    return (((size_t)(panel * 8 + kt) * 4 + kq) * 128 + m) * 8;
}

// ---------------------------------------------------------------------------
// Kernel 1 (fused prep):
//   blocks [0,512):   MLP+rownorm -> tile-format hi/lo planes (x then y)
//   blocks [512,768): key/cnt/diag zeroing + plain rownorm of x,y
// ---------------------------------------------------------------------------
static constexpr int MLP_ROWS = 32;

__global__ __launch_bounds__(256) void prep_kernel(
    const float* __restrict__ x, const float* __restrict__ y,
    const float* __restrict__ W1, const float* __restrict__ b1,
    const float* __restrict__ W2, const float* __restrict__ b2,
    unsigned short* __restrict__ pxh, unsigned short* __restrict__ pxl,
    unsigned short* __restrict__ pyh, unsigned short* __restrict__ pyl,
    unsigned short* __restrict__ xh, unsigned short* __restrict__ xl,
    unsigned short* __restrict__ yh, unsigned short* __restrict__ yl,
    ull* __restrict__ keys, int* __restrict__ cnt, float* __restrict__ diagParts)
{
    const int bid = blockIdx.x;
    const int t = threadIdx.x;

    if (bid < 512) {
        // ---------------- MLP branch ----------------
        __shared__ float sV[MLP_ROWS][D + 4];
        __shared__ float sH[MLP_ROWS][H + 4];
        __shared__ float sNrm[MLP_ROWS];

        const float* V = (bid < 256) ? x : y;
        unsigned short* Ph = (bid < 256) ? pxh : pyh;
        unsigned short* Pl = (bid < 256) ? pxl : pyl;
        const int rowBase = (bid & 255) * MLP_ROWS;

        for (int i = t; i < MLP_ROWS * (D / 4); i += 256) {
            int r = i >> 6, c4 = i & 63;
            float4 v = *reinterpret_cast<const float4*>(&V[(size_t)(rowBase + r) * D + c4 * 4]);
            sV[r][c4 * 4 + 0] = v.x; sV[r][c4 * 4 + 1] = v.y;
            sV[r][c4 * 4 + 2] = v.z; sV[r][c4 * 4 + 3] = v.w;
        }
        __syncthreads();

        {   // H = relu(V@W1 + b1)
            const int c = t & (H - 1);
            const int r0 = (t >> 7) * 16;
            float acc[16];
#pragma unroll
            for (int i = 0; i < 16; ++i) acc[i] = 0.f;
            for (int k4 = 0; k4 < D / 4; ++k4) {
                float w0 = W1[(k4 * 4 + 0) * H + c];
                float w1 = W1[(k4 * 4 + 1) * H + c];
                float w2 = W1[(k4 * 4 + 2) * H + c];
                float w3 = W1[(k4 * 4 + 3) * H + c];
#pragma unroll
                for (int i = 0; i < 16; ++i) {
                    float4 v = *reinterpret_cast<const float4*>(&sV[r0 + i][k4 * 4]);
                    acc[i] = fmaf(v.w, w3, fmaf(v.z, w2, fmaf(v.y, w1, fmaf(v.x, w0, acc[i]))));
                }
            }
            float bb = b1[c];
#pragma unroll
            for (int i = 0; i < 16; ++i) {
                float h = acc[i] + bb;
                sH[r0 + i][c] = h > 0.f ? h : 0.f;
            }
        }
        __syncthreads();

        {   // P = H@W2 + b2 -> back into sV
            const int c = t;
            float acc[MLP_ROWS];
#pragma unroll
            for (int i = 0; i < MLP_ROWS; ++i) acc[i] = 0.f;
            for (int k4 = 0; k4 < H / 4; ++k4) {
                float w0 = W2[(k4 * 4 + 0) * D + c];
                float w1 = W2[(k4 * 4 + 1) * D + c];
                float w2 = W2[(k4 * 4 + 2) * D + c];
                float w3 = W2[(k4 * 4 + 3) * D + c];
#pragma unroll
                for (int i = 0; i < MLP_ROWS; ++i) {
                    float4 v = *reinterpret_cast<const float4*>(&sH[i][k4 * 4]);
                    acc[i] = fmaf(v.w, w3, fmaf(v.z, w2, fmaf(v.y, w1, fmaf(v.x, w0, acc[i]))));
                }
            }
            float bb = b2[c];
            __syncthreads();
#pragma unroll
            for (int i = 0; i < MLP_ROWS; ++i) sV[i][c] = acc[i] + bb;
        }
        __syncthreads();

        {   // row norms
            const int wave = t >> 6, lane = t & 63;
            for (int r = wave; r < MLP_ROWS; r += 4) {
                float s = 0.f;
#pragma unroll
                for (int c = 0; c < D / 64; ++c) {
                    float v = sV[r][lane + c * 64];
                    s = fmaf(v, v, s);
                }
#pragma unroll
                for (int off = 32; off > 0; off >>= 1) s += __shfl_down(s, off);
                if (lane == 0) sNrm[r] = s;
            }
        }
        __syncthreads();

        for (int i = t; i < MLP_ROWS * (D / 4); i += 256) {
            int r = i >> 6, c4 = i & 63;
            float scale = 1.0f / fmaxf(sqrtf(sNrm[r]), 1e-12f);
            ushort4 h, l;
            split_store(sV[r][c4 * 4 + 0] * scale, &h.x, &l.x);
            split_store(sV[r][c4 * 4 + 1] * scale, &h.y, &l.y);
            split_store(sV[r][c4 * 4 + 2] * scale, &h.z, &l.z);
            split_store(sV[r][c4 * 4 + 3] * scale, &h.w, &l.w);
            int grow = rowBase + r;
            size_t g = gidx(grow >> 7, c4 >> 3, (c4 >> 1) & 3, grow & 127) + (size_t)(c4 & 1) * 4;
            *reinterpret_cast<ushort4*>(&Ph[g]) = h;
            *reinterpret_cast<ushort4*>(&Pl[g]) = l;
        }
    } else {
        // ---------------- rownorm + zeroing branch ----------------
        const int rb = bid - 512;               // 0..255
        if (t < 128) keys[rb * 128 + t] = 0ULL; // zero 32768 keys total
        if (bid == 512) {
            if (t < 128) diagParts[t] = 0.f;
            if (t < 4) cnt[t] = 0;
        }
        const int wave = t >> 6, lane = t & 63;
#pragma unroll 1
        for (int i = 0; i < 16; ++i) {
            int gr = rb * 64 + wave * 16 + i;    // 0..16383
            const float* V = (gr < N) ? x : y;
            unsigned short* Vh = (gr < N) ? xh : yh;
            unsigned short* Vl = (gr < N) ? xl : yl;
            int row = gr & (N - 1);
            float4 v = *reinterpret_cast<const float4*>(&V[(size_t)row * D + lane * 4]);
            float s = fmaf(v.x, v.x, fmaf(v.y, v.y, fmaf(v.z, v.z, v.w * v.w)));
#pragma unroll
            for (int off = 32; off > 0; off >>= 1) s += __shfl_down(s, off);
            s = __shfl(s, 0);
            float scale = 1.0f / fmaxf(sqrtf(s), 1e-12f);
            ushort4 h, l;
            split_store(v.x * scale, &h.x, &l.x);
            split_store(v.y * scale, &h.y, &l.y);
            split_store(v.z * scale, &h.z, &l.z);
            split_store(v.w * scale, &h.w, &l.w);
            size_t g = gidx(row >> 7, lane >> 3, (lane >> 1) & 3, row & 127) + (size_t)(lane & 1) * 4;
            *reinterpret_cast<ushort4*>(&Vh[g]) = h;
            *reinterpret_cast<ushort4*>(&Vl[g]) = l;
        }
    }
}

// ---------------------------------------------------------------------------
// Kernel 2: sim block 256x256, 8 waves (4x2 of 64x128). Per K-tile (K=32):
// co-stage Ah/Al/Bh/Bl (64 KB), 96 MFMA/wave (hh, lh, hl). 8 steps, dbuf-2.
// ---------------------------------------------------------------------------
__global__ __launch_bounds__(512, 2) void sim_argmax_mfma(
    const unsigned short* __restrict__ Ah, const unsigned short* __restrict__ Al,
    const unsigned short* __restrict__ Bh, const unsigned short* __restrict__ Bl,
    ull* __restrict__ rowKeys, ull* __restrict__ colKeys,
    float* __restrict__ diagParts)
{
    __shared__ s16x8 sS[2][4][1024];  // 128 KB: [slot][Ah,Al,Bh,Bl][pan*512+kq*128+m]
    __shared__ ull kbufR[256][2];     // 4 KB  row candidates (per wc)
    __shared__ ull kbufC[256][4];     // 8 KB  col candidates (per wr)
    __shared__ float sDiag[8];

    const int t = threadIdx.x;
    const int w = t >> 6, lane = t & 63;
    const int wr = w >> 1, wc = w & 1;   // 4x2 wave grid, each 64x128
    const int pan = w >> 2, wi = w & 3;  // staging role

    // grid 1024 = 32x32 tiles; bijective XCD swizzle (8 x 128)
    const int bid = blockIdx.x;
    const int swz = (bid & 7) * 128 + (bid >> 3);
    const int rowTile = swz & 31;        // fast -> A streams, B chunk L2-resident
    const int colTile = swz >> 5;
    const int rowBase = rowTile * 256;
    const int colBase = colTile * 256;

    fp32x4 acc[4][8];
#pragma unroll
    for (int i = 0; i < 4; ++i)
#pragma unroll
        for (int j = 0; j < 8; ++j) acc[i][j] = (fp32x4){0.f, 0.f, 0.f, 0.f};

    // stage K-tile kt into slot sl: 8 contiguous 1KB gload16 per wave.
    // waves 0-3 stage panel 2*tile, waves 4-7 panel 2*tile+1 (A and B alike).
#define STAGE(kt, sl)                                                               \
    do {                                                                            \
        const size_t aG = (((size_t)(rowTile * 2 + pan) * 8 + (kt)) * 512 + wi * 128 + lane) * 8; \
        const size_t bG = (((size_t)(colTile * 2 + pan) * 8 + (kt)) * 512 + wi * 128 + lane) * 8; \
        gload16(Ah + aG,       (void*)&sS[sl][0][w * 128]);                         \
        gload16(Ah + aG + 512, (void*)&sS[sl][0][w * 128 + 64]);                    \
        gload16(Al + aG,       (void*)&sS[sl][1][w * 128]);                         \
        gload16(Al + aG + 512, (void*)&sS[sl][1][w * 128 + 64]);                    \
        gload16(Bh + bG,       (void*)&sS[sl][2][w * 128]);                         \
        gload16(Bh + bG + 512, (void*)&sS[sl][2][w * 128 + 64]);                    \
        gload16(Bl + bG,       (void*)&sS[sl][3][w * 128]);                         \
        gload16(Bl + bG + 512, (void*)&sS[sl][3][w * 128 + 64]);                    \
    } while (0)

    STAGE(0, 0);
    asm volatile("s_waitcnt vmcnt(0)" ::: "memory");
    __builtin_amdgcn_s_barrier();
    __builtin_amdgcn_sched_barrier(0);

    // fragment granule bases
    const int aBase = (wr >> 1) * 512 + (lane >> 4) * 128 + (wr & 1) * 64 + (lane & 15);
    const int bBase = wc * 512 + (lane >> 4) * 128 + (lane & 15);

#pragma unroll
    for (int kt = 0; kt < 8; ++kt) {
        const int sl = kt & 1;
        if (kt < 7) STAGE(kt + 1, sl ^ 1);   // issue-early; lands by end-of-step wait
        __builtin_amdgcn_sched_barrier(0);

        s16x8 ah[4], bh[8];
#pragma unroll
        for (int f = 0; f < 4; ++f) ah[f] = sS[sl][0][aBase + f * 16];
#pragma unroll
        for (int f = 0; f < 8; ++f) bh[f] = sS[sl][2][bBase + f * 16];
        __builtin_amdgcn_s_setprio(1);
#pragma unroll
        for (int fm = 0; fm < 4; ++fm)
#pragma unroll
            for (int fn = 0; fn < 8; ++fn)
                acc[fm][fn] = __builtin_amdgcn_mfma_f32_16x16x32_bf16(ah[fm], bh[fn], acc[fm][fn], 0, 0, 0);
        __builtin_amdgcn_s_setprio(0);

        {   // low-A x high-B
            s16x8 al[4];
#pragma unroll
            for (int f = 0; f < 4; ++f) al[f] = sS[sl][1][aBase + f * 16];
            __builtin_amdgcn_s_setprio(1);
#pragma unroll
            for (int fm = 0; fm < 4; ++fm)
#pragma unroll
                for (int fn = 0; fn < 8; ++fn)
                    acc[fm][fn] = __builtin_amdgcn_mfma_f32_16x16x32_bf16(al[fm], bh[fn], acc[fm][fn], 0, 0, 0);
            __builtin_amdgcn_s_setprio(0);
        }
        {   // high-A x low-B
            s16x8 bl[8];
#pragma unroll
            for (int f = 0; f < 8; ++f) bl[f] = sS[sl][3][bBase + f * 16];
            __builtin_amdgcn_s_setprio(1);
#pragma unroll
            for (int fm = 0; fm < 4; ++fm)
#pragma unroll
                for (int fn = 0; fn < 8; ++fn)
                    acc[fm][fn] = __builtin_amdgcn_mfma_f32_16x16x32_bf16(ah[fm], bl[fn], acc[fm][fn], 0, 0, 0);
            __builtin_amdgcn_s_setprio(0);
        }

        if (kt < 7) {
            asm volatile("s_waitcnt vmcnt(0)" ::: "memory");   // next tile landed
            __builtin_amdgcn_s_barrier();                       // all waves done with sl
            __builtin_amdgcn_sched_barrier(0);
        }
    }
#undef STAGE

    // ---- diagonal (loss) partial ----
    if (rowTile == colTile) {
        float s = 0.f;
        if ((wr >> 1) == wc) {              // wave's 64x128 strip crosses diagonal
            int dr = (lane & 15) - (lane >> 4) * 4;
            if (dr >= 0 && dr < 4) {
#pragma unroll
                for (int fm = 0; fm < 4; ++fm) s += acc[fm][(wr & 1) * 4 + fm][dr];
            }
        }
#pragma unroll
        for (int off = 32; off > 0; off >>= 1) s += __shfl_down(s, off);
        if (lane == 0) sDiag[w] = s;
        __syncthreads();
        if (t == 0) {
            float d = 0.f;
#pragma unroll
            for (int i = 0; i < 8; ++i) d += sDiag[i];
            diagParts[rowTile] = d;
        }
    }

    // ---- row argmax candidates (value-first); C/D: col=lane&15, row=(lane>>4)*4+r
#pragma unroll
    for (int fm = 0; fm < 4; ++fm) {
#pragma unroll
        for (int r = 0; r < 4; ++r) {
            float m = acc[fm][0][r];
#pragma unroll
            for (int fn = 1; fn < 8; ++fn) m = fmaxf(m, acc[fm][fn][r]);
#pragma unroll
            for (int off = 1; off < 16; off <<= 1) m = fmaxf(m, __shfl_xor(m, off));
            unsigned idx = 0xFFFFFFFFu;
#pragma unroll
            for (int fn = 0; fn < 8; ++fn) {
                unsigned gcol = (unsigned)(colBase + wc * 128 + fn * 16 + (lane & 15));
                if (acc[fm][fn][r] == m && gcol < idx) idx = gcol;
            }
#pragma unroll
            for (int off = 1; off < 16; off <<= 1) {
                unsigned o = __shfl_xor(idx, off);
                if (o < idx) idx = o;
            }
            if ((lane & 15) == 0)
                kbufR[wr * 64 + fm * 16 + (lane >> 4) * 4 + r][wc] =
                    ((ull)f2ord(m) << 32) | (unsigned)(~idx);
        }
    }

    // ---- col argmax candidates ----
#pragma unroll
    for (int fn = 0; fn < 8; ++fn) {
        int colLoc = wc * 128 + fn * 16 + (lane & 15);
        float m = -3.4e38f;
#pragma unroll
        for (int fm = 0; fm < 4; ++fm) {
            float m01 = fmaxf(acc[fm][fn][0], acc[fm][fn][1]);
            float m23 = fmaxf(acc[fm][fn][2], acc[fm][fn][3]);
            m = fmaxf(m, fmaxf(m01, m23));
        }
        m = fmaxf(m, __shfl_xor(m, 16));
        m = fmaxf(m, __shfl_xor(m, 32));
        unsigned idx = 0xFFFFFFFFu;
#pragma unroll
        for (int fm = 0; fm < 4; ++fm) {
#pragma unroll
            for (int r = 0; r < 4; ++r) {
                unsigned grow = (unsigned)(rowBase + wr * 64 + fm * 16 + (lane >> 4) * 4 + r);
                if (acc[fm][fn][r] == m && grow < idx) idx = grow;
            }
        }
        {
            unsigned o = __shfl_xor(idx, 16);
            if (o < idx) idx = o;
            o = __shfl_xor(idx, 32);
            if (o < idx) idx = o;
        }
        if (lane < 16)
            kbufC[colLoc][wr] = ((ull)f2ord(m) << 32) | (unsigned)(~idx);
    }

    __syncthreads();

    // ---- one global atomic per row / col ----
    if (t < 256) {
        ull best = umax64(kbufR[t][0], kbufR[t][1]);
        atomicMax(&rowKeys[rowBase + t], best);
    } else {
        int c = t - 256;
        ull best = umax64(umax64(kbufC[c][0], kbufC[c][1]), umax64(kbufC[c][2], kbufC[c][3]));
        atomicMax(&colKeys[colBase + c], best);
    }
}

// ---------------------------------------------------------------------------
// Kernel 3: parallel deterministic counts (int atomics).
// ---------------------------------------------------------------------------
__global__ __launch_bounds__(256) void count_kernel(const ull* __restrict__ keys, int* __restrict__ cnt)
{
    const int t = threadIdx.x;
    const int i = blockIdx.x * 256 + t;
    const int lane = t & 63;
#pragma unroll
    for (int a = 0; a < 4; ++a) {
        int s = ((~(unsigned)keys[a * N + i]) == (unsigned)i);
#pragma unroll
        for (int off = 32; off > 0; off >>= 1) s += __shfl_down(s, off);
        if (lane == 0) atomicAdd(&cnt[a], s);
    }
}

// ---------------------------------------------------------------------------
// Kernel 4: final scalars.
// ---------------------------------------------------------------------------
__global__ __launch_bounds__(64) void final_kernel(
    const float* __restrict__ diagParts, const int* __restrict__ cnt, float* __restrict__ out)
{
    const int lane = threadIdx.x;
    double vx = (double)diagParts[lane];
    double vy = (double)diagParts[64 + lane];
#pragma unroll
    for (int off = 32; off > 0; off >>= 1) {
        vx += __shfl_down(vx, off);
        vy += __shfl_down(vy, off);
    }
    if (lane == 0) {
        float invN = 1.0f / (float)N;
        out[0] = (float)(-0.5 * (vx + vy) / (double)N);
        out[1] = 0.5f * ((float)cnt[1] * invN) + (float)cnt[0] * invN;
        out[2] = 0.5f * ((float)cnt[3] * invN) + (float)cnt[2] * invN;
    }
}

// ---------------------------------------------------------------------------
extern "C" void kernel_launch(void* const* d_in, const int* in_sizes, int n_in,
                              void* d_out, int out_size, void* d_ws, size_t ws_size,
                              hipStream_t stream)
{
    (void)in_sizes; (void)n_in; (void)out_size; (void)ws_size;
    const float* x  = (const float*)d_in[0];
    const float* y  = (const float*)d_in[1];
    const float* W1 = (const float*)d_in[2];
    const float* b1 = (const float*)d_in[3];
    const float* W2 = (const float*)d_in[4];
    const float* b2 = (const float*)d_in[5];
    float* out = (float*)d_out;

    const size_t ND = (size_t)N * D;
    unsigned short* pxh = (unsigned short*)d_ws;   // 8 bf16 planes x 4 MB = 32 MB
    unsigned short* pxl = pxh + ND;
    unsigned short* pyh = pxl + ND;
    unsigned short* pyl = pyh + ND;
    unsigned short* xh  = pyl + ND;
    unsigned short* xl  = xh + ND;
    unsigned short* yh  = xl + ND;
    unsigned short* yl  = yh + ND;
    ull* keys = (ull*)(yl + ND);                   // 256 KB
    ull* rkx = keys + 0 * N;
    ull* ckx = keys + 1 * N;
    ull* rky = keys + 2 * N;
    ull* cky = keys + 3 * N;
    float* diagParts = (float*)(keys + 4 * N);     // 128 floats
    int* cnt = (int*)(diagParts + 128);            // 4 ints

    prep_kernel<<<768, 256, 0, stream>>>(x, y, W1, b1, W2, b2,
                                         pxh, pxl, pyh, pyl, xh, xl, yh, yl,
                                         keys, cnt, diagParts);

    sim_argmax_mfma<<<1024, 512, 0, stream>>>(pxh, pxl, yh, yl, rkx, ckx, diagParts);
    sim_argmax_mfma<<<1024, 512, 0, stream>>>(pyh, pyl, xh, xl, rky, cky, diagParts + 64);

    count_kernel<<<32, 256, 0, stream>>>(keys, cnt);
    final_kernel<<<1, 64, 0, stream>>>(diagParts, cnt, out);
}

// Round 8
// 370.851 us; speedup vs baseline: 2.3138x; 2.3138x over previous
//
#include <hip/hip_runtime.h>

// SimSiam: N=8192, D=256, H=128, fp32 in/out.
// Sim via split-fp32 bf16 MFMA: sim = Ah·Bh^T + Al·Bh^T + Ah·Bl^T.
// 256x128 tile, 8 waves (4x2 of 64x64), all four planes co-staged per K-tile,
// ring-3 LDS with counted vmcnt(6) (distance-2 prefetch, no drain in loop).
// Planes in MFMA-tile format:
//   granule16B(panel,kt,kq,m) = ((panel*8+kt)*4+kq)*128+m   (panel = 128 rows)
// Loss = mean(diag(sim)) from diagonal blocks' accumulators.

static constexpr int N = 8192;
static constexpr int D = 256;
static constexpr int H = 128;

typedef __attribute__((ext_vector_type(8))) short s16x8;
typedef __attribute__((ext_vector_type(4))) float fp32x4;
typedef unsigned long long ull;

__device__ __forceinline__ unsigned f2ord(float f) {
    unsigned u = __float_as_uint(f);
    return (u & 0x80000000u) ? ~u : (u | 0x80000000u);
}
__device__ __forceinline__ ull umax64(ull a, ull b) { return a > b ? a : b; }
__device__ __forceinline__ unsigned short bf16_rtne(float f) {
    unsigned u = __float_as_uint(f);
    unsigned r = 0x7FFFu + ((u >> 16) & 1u);
    return (unsigned short)((u + r) >> 16);
}
__device__ __forceinline__ float bf_f(unsigned short h) {
    return __uint_as_float((unsigned)h << 16);
}
__device__ __forceinline__ void split_store(float f, unsigned short* h, unsigned short* l) {
    unsigned short hb = bf16_rtne(f);
    *h = hb;
    *l = bf16_rtne(f - bf_f(hb));
}
__device__ __forceinline__ void gload16(const unsigned short* g, void* lds) {
    __builtin_amdgcn_global_load_lds(
        (const __attribute__((address_space(1))) unsigned int*)g,
        (__attribute__((address_space(3))) unsigned int*)lds, 16, 0, 0);
}
// tile-format granule index (in ushort units)
__device__ __forceinline__ size_t gidx(int panel, int kt, int kq, int m) {
    return (((size_t)(panel * 8 + kt) * 4 + kq) * 128 + m) * 8;
}

// ---------------------------------------------------------------------------
// Kernel 1 (fused prep):
//   blocks [0,512):   MLP+rownorm -> tile-format hi/lo planes (x then y)
//   blocks [512,768): key/cnt/diag zeroing + plain rownorm of x,y
// ---------------------------------------------------------------------------
static constexpr int MLP_ROWS = 32;

__global__ __launch_bounds__(256) void prep_kernel(
    const float* __restrict__ x, const float* __restrict__ y,
    const float* __restrict__ W1, const float* __restrict__ b1,
    const float* __restrict__ W2, const float* __restrict__ b2,
    unsigned short* __restrict__ pxh, unsigned short* __restrict__ pxl,
    unsigned short* __restrict__ pyh, unsigned short* __restrict__ pyl,
    unsigned short* __restrict__ xh, unsigned short* __restrict__ xl,
    unsigned short* __restrict__ yh, unsigned short* __restrict__ yl,
    ull* __restrict__ keys, int* __restrict__ cnt, float* __restrict__ diagParts)
{
    const int bid = blockIdx.x;
    const int t = threadIdx.x;

    if (bid < 512) {
        // ---------------- MLP branch ----------------
        __shared__ float sV[MLP_ROWS][D + 4];
        __shared__ float sH[MLP_ROWS][H + 4];
        __shared__ float sNrm[MLP_ROWS];

        const float* V = (bid < 256) ? x : y;
        unsigned short* Ph = (bid < 256) ? pxh : pyh;
        unsigned short* Pl = (bid < 256) ? pxl : pyl;
        const int rowBase = (bid & 255) * MLP_ROWS;

        for (int i = t; i < MLP_ROWS * (D / 4); i += 256) {
            int r = i >> 6, c4 = i & 63;
            float4 v = *reinterpret_cast<const float4*>(&V[(size_t)(rowBase + r) * D + c4 * 4]);
            sV[r][c4 * 4 + 0] = v.x; sV[r][c4 * 4 + 1] = v.y;
            sV[r][c4 * 4 + 2] = v.z; sV[r][c4 * 4 + 3] = v.w;
        }
        __syncthreads();

        {   // H = relu(V@W1 + b1)
            const int c = t & (H - 1);
            const int r0 = (t >> 7) * 16;
            float acc[16];
#pragma unroll
            for (int i = 0; i < 16; ++i) acc[i] = 0.f;
            for (int k4 = 0; k4 < D / 4; ++k4) {
                float w0 = W1[(k4 * 4 + 0) * H + c];
                float w1 = W1[(k4 * 4 + 1) * H + c];
                float w2 = W1[(k4 * 4 + 2) * H + c];
                float w3 = W1[(k4 * 4 + 3) * H + c];
#pragma unroll
                for (int i = 0; i < 16; ++i) {
                    float4 v = *reinterpret_cast<const float4*>(&sV[r0 + i][k4 * 4]);
                    acc[i] = fmaf(v.w, w3, fmaf(v.z, w2, fmaf(v.y, w1, fmaf(v.x, w0, acc[i]))));
                }
            }
            float bb = b1[c];
#pragma unroll
            for (int i = 0; i < 16; ++i) {
                float h = acc[i] + bb;
                sH[r0 + i][c] = h > 0.f ? h : 0.f;
            }
        }
        __syncthreads();

        {   // P = H@W2 + b2 -> back into sV
            const int c = t;
            float acc[MLP_ROWS];
#pragma unroll
            for (int i = 0; i < MLP_ROWS; ++i) acc[i] = 0.f;
            for (int k4 = 0; k4 < H / 4; ++k4) {
                float w0 = W2[(k4 * 4 + 0) * D + c];
                float w1 = W2[(k4 * 4 + 1) * D + c];
                float w2 = W2[(k4 * 4 + 2) * D + c];
                float w3 = W2[(k4 * 4 + 3) * D + c];
#pragma unroll
                for (int i = 0; i < MLP_ROWS; ++i) {
                    float4 v = *reinterpret_cast<const float4*>(&sH[i][k4 * 4]);
                    acc[i] = fmaf(v.w, w3, fmaf(v.z, w2, fmaf(v.y, w1, fmaf(v.x, w0, acc[i]))));
                }
            }
            float bb = b2[c];
            __syncthreads();
#pragma unroll
            for (int i = 0; i < MLP_ROWS; ++i) sV[i][c] = acc[i] + bb;
        }
        __syncthreads();

        {   // row norms
            const int wave = t >> 6, lane = t & 63;
            for (int r = wave; r < MLP_ROWS; r += 4) {
                float s = 0.f;
#pragma unroll
                for (int c = 0; c < D / 64; ++c) {
                    float v = sV[r][lane + c * 64];
                    s = fmaf(v, v, s);
                }
#pragma unroll
                for (int off = 32; off > 0; off >>= 1) s += __shfl_down(s, off);
                if (lane == 0) sNrm[r] = s;
            }
        }
        __syncthreads();

        for (int i = t; i < MLP_ROWS * (D / 4); i += 256) {
            int r = i >> 6, c4 = i & 63;
            float scale = 1.0f / fmaxf(sqrtf(sNrm[r]), 1e-12f);
            ushort4 h, l;
            split_store(sV[r][c4 * 4 + 0] * scale, &h.x, &l.x);
            split_store(sV[r][c4 * 4 + 1] * scale, &h.y, &l.y);
            split_store(sV[r][c4 * 4 + 2] * scale, &h.z, &l.z);
            split_store(sV[r][c4 * 4 + 3] * scale, &h.w, &l.w);
            int grow = rowBase + r;
            size_t g = gidx(grow >> 7, c4 >> 3, (c4 >> 1) & 3, grow & 127) + (size_t)(c4 & 1) * 4;
            *reinterpret_cast<ushort4*>(&Ph[g]) = h;
            *reinterpret_cast<ushort4*>(&Pl[g]) = l;
        }
    } else {
        // ---------------- rownorm + zeroing branch ----------------
        const int rb = bid - 512;               // 0..255
        if (t < 128) keys[rb * 128 + t] = 0ULL; // zero 32768 keys total
        if (bid == 512) {
            if (t < 128) diagParts[t] = 0.f;
            if (t < 4) cnt[t] = 0;
        }
        const int wave = t >> 6, lane = t & 63;
#pragma unroll 1
        for (int i = 0; i < 16; ++i) {
            int gr = rb * 64 + wave * 16 + i;    // 0..16383
            const float* V = (gr < N) ? x : y;
            unsigned short* Vh = (gr < N) ? xh : yh;
            unsigned short* Vl = (gr < N) ? xl : yl;
            int row = gr & (N - 1);
            float4 v = *reinterpret_cast<const float4*>(&V[(size_t)row * D + lane * 4]);
            float s = fmaf(v.x, v.x, fmaf(v.y, v.y, fmaf(v.z, v.z, v.w * v.w)));
#pragma unroll
            for (int off = 32; off > 0; off >>= 1) s += __shfl_down(s, off);
            s = __shfl(s, 0);
            float scale = 1.0f / fmaxf(sqrtf(s), 1e-12f);
            ushort4 h, l;
            split_store(v.x * scale, &h.x, &l.x);
            split_store(v.y * scale, &h.y, &l.y);
            split_store(v.z * scale, &h.z, &l.z);
            split_store(v.w * scale, &h.w, &l.w);
            size_t g = gidx(row >> 7, lane >> 3, (lane >> 1) & 3, row & 127) + (size_t)(lane & 1) * 4;
            *reinterpret_cast<ushort4*>(&Vh[g]) = h;
            *reinterpret_cast<ushort4*>(&Vl[g]) = l;
        }
    }
}

// ---------------------------------------------------------------------------
// Kernel 2: sim block 256x128, 8 waves (4x2 of 64x64). Per K-tile (K=32):
// co-stage Ah/Al/Bh/Bl (48 KB slot), 48 MFMA/wave. Ring-3, counted vmcnt(6).
// LDS slot layout (granule units): [0,1024) Ah, [1024,2048) Al,
// [2048,2560) Bh, [2560,3072) Bl; within A: pan*512 + kq*128 + m.
// ---------------------------------------------------------------------------
__global__ __launch_bounds__(512, 2) void sim_argmax_mfma(
    const unsigned short* __restrict__ Ah, const unsigned short* __restrict__ Al,
    const unsigned short* __restrict__ Bh, const unsigned short* __restrict__ Bl,
    ull* __restrict__ rowKeys, ull* __restrict__ colKeys,
    float* __restrict__ diagParts)
{
    __shared__ s16x8 sS[3][3072];     // 144 KB ring
    __shared__ ull kbufR[256][2];     // 4 KB
    __shared__ ull kbufC[128][4];     // 4 KB
    __shared__ float sDiag[8];

    const int t = threadIdx.x;
    const int w = t >> 6, lane = t & 63;
    const int wr = w >> 1, wc = w & 1;   // 4x2 wave grid, each 64x64

    // grid 2048 = 32 rowTiles x 64 colTiles; bijective XCD swizzle (8 x 256)
    const int bid = blockIdx.x;
    const int swz = (bid & 7) * 256 + (bid >> 3);
    const int rowTile = swz & 31;        // fast -> A streams, B chunk L2-resident
    const int colTile = swz >> 5;
    const int rowBase = rowTile * 256;
    const int colBase = colTile * 128;

    fp32x4 acc[4][4];
#pragma unroll
    for (int i = 0; i < 4; ++i)
#pragma unroll
        for (int j = 0; j < 4; ++j) acc[i][j] = (fp32x4){0.f, 0.f, 0.f, 0.f};

    const int pA0 = rowTile * 2;
    // per-wave load coordinates
    const int LA0 = w * 128 + lane;          // A granules: chunks LA0, LA0+64
    const int LB0 = w * 64 + lane;           // B granule chunk

    // 6 gload16 per wave per K-tile (lane-contiguous 1KB each)
#define STAGE(kt, sl)                                                                          \
    do {                                                                                       \
        const size_t a0 = ((size_t)(pA0 + (LA0 >> 9)) * 4096 + (size_t)(kt) * 512 + (LA0 & 511)) * 8; \
        const int LA1 = LA0 + 64;                                                              \
        const size_t a1 = ((size_t)(pA0 + (LA1 >> 9)) * 4096 + (size_t)(kt) * 512 + (LA1 & 511)) * 8; \
        const size_t b0 = ((size_t)colTile * 4096 + (size_t)(kt) * 512 + LB0) * 8;             \
        gload16(Ah + a0, (void*)&sS[sl][LA0]);                                                 \
        gload16(Ah + a1, (void*)&sS[sl][LA1]);                                                 \
        gload16(Al + a0, (void*)&sS[sl][1024 + LA0]);                                          \
        gload16(Al + a1, (void*)&sS[sl][1024 + LA1]);                                          \
        gload16(Bh + b0, (void*)&sS[sl][2048 + LB0]);                                          \
        gload16(Bl + b0, (void*)&sS[sl][2560 + LB0]);                                          \
    } while (0)

    STAGE(0, 0);
    STAGE(1, 1);

    // fragment granule bases
    const int aBase = (wr >> 1) * 512 + (lane >> 4) * 128 + (wr & 1) * 64 + (lane & 15);
    const int bBase = 2048 + (lane >> 4) * 128 + wc * 64 + (lane & 15);

#pragma unroll
    for (int kt = 0; kt < 8; ++kt) {
        if (kt < 7) { asm volatile("s_waitcnt vmcnt(6)" ::: "memory"); }
        else        { asm volatile("s_waitcnt vmcnt(0)" ::: "memory"); }
        __builtin_amdgcn_sched_barrier(0);
        __builtin_amdgcn_s_barrier();      // all waves' tile-kt loads landed;
        __builtin_amdgcn_sched_barrier(0); // slot (kt+2)%3 free (read in kt-1)
        const int sl = kt % 3;
        if (kt < 6) STAGE(kt + 2, (kt + 2) % 3);
        __builtin_amdgcn_sched_barrier(0);

        s16x8 ah[4], bh[4];
#pragma unroll
        for (int f = 0; f < 4; ++f) ah[f] = sS[sl][aBase + f * 16];
#pragma unroll
        for (int f = 0; f < 4; ++f) bh[f] = sS[sl][bBase + f * 16];
        __builtin_amdgcn_s_setprio(1);
#pragma unroll
        for (int fm = 0; fm < 4; ++fm)
#pragma unroll
            for (int fn = 0; fn < 4; ++fn)
                acc[fm][fn] = __builtin_amdgcn_mfma_f32_16x16x32_bf16(ah[fm], bh[fn], acc[fm][fn], 0, 0, 0);
        __builtin_amdgcn_s_setprio(0);

        {   // low-A x high-B
            s16x8 al[4];
#pragma unroll
            for (int f = 0; f < 4; ++f) al[f] = sS[sl][1024 + aBase + f * 16];
            __builtin_amdgcn_s_setprio(1);
#pragma unroll
            for (int fm = 0; fm < 4; ++fm)
#pragma unroll
                for (int fn = 0; fn < 4; ++fn)
                    acc[fm][fn] = __builtin_amdgcn_mfma_f32_16x16x32_bf16(al[fm], bh[fn], acc[fm][fn], 0, 0, 0);
            __builtin_amdgcn_s_setprio(0);
        }
        {   // high-A x low-B
            s16x8 bl[4];
#pragma unroll
            for (int f = 0; f < 4; ++f) bl[f] = sS[sl][512 + bBase + f * 16];
            __builtin_amdgcn_s_setprio(1);
#pragma unroll
            for (int fm = 0; fm < 4; ++fm)
#pragma unroll
                for (int fn = 0; fn < 4; ++fn)
                    acc[fm][fn] = __builtin_amdgcn_mfma_f32_16x16x32_bf16(ah[fm], bl[fn], acc[fm][fn], 0, 0, 0);
            __builtin_amdgcn_s_setprio(0);
        }
    }
#undef STAGE

    // ---- diagonal (loss) partial (static acc indices only) ----
    if (rowTile == (colTile >> 1)) {
        float s = 0.f;
        if (wr == wc + 2 * (colTile & 1)) {   // wave's 64x64 sits on the diagonal
            const int cl = lane & 15, rh = lane >> 4;
#pragma unroll
            for (int fm = 0; fm < 4; ++fm) {
#pragma unroll
                for (int r = 0; r < 4; ++r) {
                    if (cl == rh * 4 + r) s += acc[fm][fm][r];
                }
            }
        }
#pragma unroll
        for (int off = 32; off > 0; off >>= 1) s += __shfl_down(s, off);
        if (lane == 0) sDiag[w] = s;
        __syncthreads();
        if (t == 0) {
            float d = 0.f;
#pragma unroll
            for (int i = 0; i < 8; ++i) d += sDiag[i];
            diagParts[colTile] = d;
        }
    }

    // ---- row argmax candidates (value-first); C/D: col=lane&15, row=(lane>>4)*4+r
#pragma unroll
    for (int fm = 0; fm < 4; ++fm) {
#pragma unroll
        for (int r = 0; r < 4; ++r) {
            int rowLoc = wr * 64 + fm * 16 + (lane >> 4) * 4 + r;
            float m = fmaxf(fmaxf(acc[fm][0][r], acc[fm][1][r]), fmaxf(acc[fm][2][r], acc[fm][3][r]));
#pragma unroll
            for (int off = 1; off < 16; off <<= 1) m = fmaxf(m, __shfl_xor(m, off));
            unsigned idx = 0xFFFFFFFFu;
#pragma unroll
            for (int fn = 0; fn < 4; ++fn) {
                unsigned gcol = (unsigned)(colBase + wc * 64 + fn * 16 + (lane & 15));
                if (acc[fm][fn][r] == m && gcol < idx) idx = gcol;
            }
#pragma unroll
            for (int off = 1; off < 16; off <<= 1) {
                unsigned o = __shfl_xor(idx, off);
                if (o < idx) idx = o;
            }
            if ((lane & 15) == 0)
                kbufR[rowLoc][wc] = ((ull)f2ord(m) << 32) | (unsigned)(~idx);
        }
    }

    // ---- col argmax candidates ----
#pragma unroll
    for (int fn = 0; fn < 4; ++fn) {
        int colLoc = wc * 64 + fn * 16 + (lane & 15);
        float m = -3.4e38f;
#pragma unroll
        for (int fm = 0; fm < 4; ++fm) {
            float m01 = fmaxf(acc[fm][fn][0], acc[fm][fn][1]);
            float m23 = fmaxf(acc[fm][fn][2], acc[fm][fn][3]);
            m = fmaxf(m, fmaxf(m01, m23));
        }
        m = fmaxf(m, __shfl_xor(m, 16));
        m = fmaxf(m, __shfl_xor(m, 32));
        unsigned idx = 0xFFFFFFFFu;
#pragma unroll
        for (int fm = 0; fm < 4; ++fm) {
#pragma unroll
            for (int r = 0; r < 4; ++r) {
                unsigned grow = (unsigned)(rowBase + wr * 64 + fm * 16 + (lane >> 4) * 4 + r);
                if (acc[fm][fn][r] == m && grow < idx) idx = grow;
            }
        }
        {
            unsigned o = __shfl_xor(idx, 16);
            if (o < idx) idx = o;
            o = __shfl_xor(idx, 32);
            if (o < idx) idx = o;
        }
        if (lane < 16)
            kbufC[colLoc][wr] = ((ull)f2ord(m) << 32) | (unsigned)(~idx);
    }

    __syncthreads();

    // ---- one global atomic per row / col ----
    if (t < 256) {
        ull best = umax64(kbufR[t][0], kbufR[t][1]);
        atomicMax(&rowKeys[rowBase + t], best);
    } else if (t < 384) {
        int c = t - 256;
        ull best = umax64(umax64(kbufC[c][0], kbufC[c][1]), umax64(kbufC[c][2], kbufC[c][3]));
        atomicMax(&colKeys[colBase + c], best);
    }
}

// ---------------------------------------------------------------------------
// Kernel 3: parallel deterministic counts (int atomics).
// ---------------------------------------------------------------------------
__global__ __launch_bounds__(256) void count_kernel(const ull* __restrict__ keys, int* __restrict__ cnt)
{
    const int t = threadIdx.x;
    const int i = blockIdx.x * 256 + t;
    const int lane = t & 63;
#pragma unroll
    for (int a = 0; a < 4; ++a) {
        int s = ((~(unsigned)keys[a * N + i]) == (unsigned)i);
#pragma unroll
        for (int off = 32; off > 0; off >>= 1) s += __shfl_down(s, off);
        if (lane == 0) atomicAdd(&cnt[a], s);
    }
}

// ---------------------------------------------------------------------------
// Kernel 4: final scalars.
// ---------------------------------------------------------------------------
__global__ __launch_bounds__(64) void final_kernel(
    const float* __restrict__ diagParts, const int* __restrict__ cnt, float* __restrict__ out)
{
    const int lane = threadIdx.x;
    double vx = (double)diagParts[lane];
    double vy = (double)diagParts[64 + lane];
#pragma unroll
    for (int off = 32; off > 0; off >>= 1) {
        vx += __shfl_down(vx, off);
        vy += __shfl_down(vy, off);
    }
    if (lane == 0) {
        float invN = 1.0f / (float)N;
        out[0] = (float)(-0.5 * (vx + vy) / (double)N);
        out[1] = 0.5f * ((float)cnt[1] * invN) + (float)cnt[0] * invN;
        out[2] = 0.5f * ((float)cnt[3] * invN) + (float)cnt[2] * invN;
    }
}

// ---------------------------------------------------------------------------
extern "C" void kernel_launch(void* const* d_in, const int* in_sizes, int n_in,
                              void* d_out, int out_size, void* d_ws, size_t ws_size,
                              hipStream_t stream)
{
    (void)in_sizes; (void)n_in; (void)out_size; (void)ws_size;
    const float* x  = (const float*)d_in[0];
    const float* y  = (const float*)d_in[1];
    const float* W1 = (const float*)d_in[2];
    const float* b1 = (const float*)d_in[3];
    const float* W2 = (const float*)d_in[4];
    const float* b2 = (const float*)d_in[5];
    float* out = (float*)d_out;

    const size_t ND = (size_t)N * D;
    unsigned short* pxh = (unsigned short*)d_ws;   // 8 bf16 planes x 4 MB = 32 MB
    unsigned short* pxl = pxh + ND;
    unsigned short* pyh = pxl + ND;
    unsigned short* pyl = pyh + ND;
    unsigned short* xh  = pyl + ND;
    unsigned short* xl  = xh + ND;
    unsigned short* yh  = xl + ND;
    unsigned short* yl  = yh + ND;
    ull* keys = (ull*)(yl + ND);                   // 256 KB
    ull* rkx = keys + 0 * N;
    ull* ckx = keys + 1 * N;
    ull* rky = keys + 2 * N;
    ull* cky = keys + 3 * N;
    float* diagParts = (float*)(keys + 4 * N);     // 128 floats
    int* cnt = (int*)(diagParts + 128);            // 4 ints

    prep_kernel<<<768, 256, 0, stream>>>(x, y, W1, b1, W2, b2,
                                         pxh, pxl, pyh, pyl, xh, xl, yh, yl,
                                         keys, cnt, diagParts);

    sim_argmax_mfma<<<2048, 512, 0, stream>>>(pxh, pxl, yh, yl, rkx, ckx, diagParts);
    sim_argmax_mfma<<<2048, 512, 0, stream>>>(pyh, pyl, xh, xl, rky, cky, diagParts + 64);

    count_kernel<<<32, 256, 0, stream>>>(keys, cnt);
    final_kernel<<<1, 64, 0, stream>>>(diagParts, cnt, out);
}

// Round 9
// 350.712 us; speedup vs baseline: 2.4466x; 1.0574x over previous
//
#include <hip/hip_runtime.h>

// SimSiam: N=8192, D=256, H=128, fp32 in/out.
// Sim via split-fp32 bf16 MFMA: sim = Ah·Bh^T + Al·Bh^T + Ah·Bl^T.
// m201-style phase-interleaved schedule: 256x256 tile, 8 waves (2Mx4N of
// 128x64), BK=32, ring-2 co-staged slots, 3 phases/K-tile (hh/lh/hl),
// barriers bracketing each 32-MFMA cluster, vmcnt(0) once per K-tile.
// Planes in MFMA-tile format:
//   granule16B(panel,kt,kq,m) = ((panel*8+kt)*4+kq)*128+m   (panel = 128 rows)
// 2D super-tile XCD swizzle: XCD owns 8 rowTiles x 16 colTiles (A 2MB + B
// panel 256KB L2-resident). Loss = mean(diag(sim)) from diagonal blocks.

static constexpr int N = 8192;
static constexpr int D = 256;
static constexpr int H = 128;

typedef __attribute__((ext_vector_type(8))) short s16x8;
typedef __attribute__((ext_vector_type(4))) float fp32x4;
typedef unsigned long long ull;

__device__ __forceinline__ unsigned f2ord(float f) {
    unsigned u = __float_as_uint(f);
    return (u & 0x80000000u) ? ~u : (u | 0x80000000u);
}
__device__ __forceinline__ ull umax64(ull a, ull b) { return a > b ? a : b; }
__device__ __forceinline__ unsigned short bf16_rtne(float f) {
    unsigned u = __float_as_uint(f);
    unsigned r = 0x7FFFu + ((u >> 16) & 1u);
    return (unsigned short)((u + r) >> 16);
}
__device__ __forceinline__ float bf_f(unsigned short h) {
    return __uint_as_float((unsigned)h << 16);
}
__device__ __forceinline__ void split_store(float f, unsigned short* h, unsigned short* l) {
    unsigned short hb = bf16_rtne(f);
    *h = hb;
    *l = bf16_rtne(f - bf_f(hb));
}
__device__ __forceinline__ void gload16(const unsigned short* g, void* lds) {
    __builtin_amdgcn_global_load_lds(
        (const __attribute__((address_space(1))) unsigned int*)g,
        (__attribute__((address_space(3))) unsigned int*)lds, 16, 0, 0);
}
// tile-format granule index (in ushort units)
__device__ __forceinline__ size_t gidx(int panel, int kt, int kq, int m) {
    return (((size_t)(panel * 8 + kt) * 4 + kq) * 128 + m) * 8;
}

// ---------------------------------------------------------------------------
// Kernel 1 (fused prep):
//   blocks [0,512):   MLP+rownorm -> tile-format hi/lo planes (x then y)
//   blocks [512,768): key/cnt/diag zeroing + plain rownorm of x,y
// ---------------------------------------------------------------------------
static constexpr int MLP_ROWS = 32;

__global__ __launch_bounds__(256) void prep_kernel(
    const float* __restrict__ x, const float* __restrict__ y,
    const float* __restrict__ W1, const float* __restrict__ b1,
    const float* __restrict__ W2, const float* __restrict__ b2,
    unsigned short* __restrict__ pxh, unsigned short* __restrict__ pxl,
    unsigned short* __restrict__ pyh, unsigned short* __restrict__ pyl,
    unsigned short* __restrict__ xh, unsigned short* __restrict__ xl,
    unsigned short* __restrict__ yh, unsigned short* __restrict__ yl,
    ull* __restrict__ keys, int* __restrict__ cnt, float* __restrict__ diagParts)
{
    const int bid = blockIdx.x;
    const int t = threadIdx.x;

    if (bid < 512) {
        // ---------------- MLP branch ----------------
        __shared__ float sV[MLP_ROWS][D + 4];
        __shared__ float sH[MLP_ROWS][H + 4];
        __shared__ float sNrm[MLP_ROWS];

        const float* V = (bid < 256) ? x : y;
        unsigned short* Ph = (bid < 256) ? pxh : pyh;
        unsigned short* Pl = (bid < 256) ? pxl : pyl;
        const int rowBase = (bid & 255) * MLP_ROWS;

        for (int i = t; i < MLP_ROWS * (D / 4); i += 256) {
            int r = i >> 6, c4 = i & 63;
            float4 v = *reinterpret_cast<const float4*>(&V[(size_t)(rowBase + r) * D + c4 * 4]);
            sV[r][c4 * 4 + 0] = v.x; sV[r][c4 * 4 + 1] = v.y;
            sV[r][c4 * 4 + 2] = v.z; sV[r][c4 * 4 + 3] = v.w;
        }
        __syncthreads();

        {   // H = relu(V@W1 + b1)
            const int c = t & (H - 1);
            const int r0 = (t >> 7) * 16;
            float acc[16];
#pragma unroll
            for (int i = 0; i < 16; ++i) acc[i] = 0.f;
            for (int k4 = 0; k4 < D / 4; ++k4) {
                float w0 = W1[(k4 * 4 + 0) * H + c];
                float w1 = W1[(k4 * 4 + 1) * H + c];
                float w2 = W1[(k4 * 4 + 2) * H + c];
                float w3 = W1[(k4 * 4 + 3) * H + c];
#pragma unroll
                for (int i = 0; i < 16; ++i) {
                    float4 v = *reinterpret_cast<const float4*>(&sV[r0 + i][k4 * 4]);
                    acc[i] = fmaf(v.w, w3, fmaf(v.z, w2, fmaf(v.y, w1, fmaf(v.x, w0, acc[i]))));
                }
            }
            float bb = b1[c];
#pragma unroll
            for (int i = 0; i < 16; ++i) {
                float h = acc[i] + bb;
                sH[r0 + i][c] = h > 0.f ? h : 0.f;
            }
        }
        __syncthreads();

        {   // P = H@W2 + b2 -> back into sV
            const int c = t;
            float acc[MLP_ROWS];
#pragma unroll
            for (int i = 0; i < MLP_ROWS; ++i) acc[i] = 0.f;
            for (int k4 = 0; k4 < H / 4; ++k4) {
                float w0 = W2[(k4 * 4 + 0) * D + c];
                float w1 = W2[(k4 * 4 + 1) * D + c];
                float w2 = W2[(k4 * 4 + 2) * D + c];
                float w3 = W2[(k4 * 4 + 3) * D + c];
#pragma unroll
                for (int i = 0; i < MLP_ROWS; ++i) {
                    float4 v = *reinterpret_cast<const float4*>(&sH[i][k4 * 4]);
                    acc[i] = fmaf(v.w, w3, fmaf(v.z, w2, fmaf(v.y, w1, fmaf(v.x, w0, acc[i]))));
                }
            }
            float bb = b2[c];
            __syncthreads();
#pragma unroll
            for (int i = 0; i < MLP_ROWS; ++i) sV[i][c] = acc[i] + bb;
        }
        __syncthreads();

        {   // row norms
            const int wave = t >> 6, lane = t & 63;
            for (int r = wave; r < MLP_ROWS; r += 4) {
                float s = 0.f;
#pragma unroll
                for (int c = 0; c < D / 64; ++c) {
                    float v = sV[r][lane + c * 64];
                    s = fmaf(v, v, s);
                }
#pragma unroll
                for (int off = 32; off > 0; off >>= 1) s += __shfl_down(s, off);
                if (lane == 0) sNrm[r] = s;
            }
        }
        __syncthreads();

        for (int i = t; i < MLP_ROWS * (D / 4); i += 256) {
            int r = i >> 6, c4 = i & 63;
            float scale = 1.0f / fmaxf(sqrtf(sNrm[r]), 1e-12f);
            ushort4 h, l;
            split_store(sV[r][c4 * 4 + 0] * scale, &h.x, &l.x);
            split_store(sV[r][c4 * 4 + 1] * scale, &h.y, &l.y);
            split_store(sV[r][c4 * 4 + 2] * scale, &h.z, &l.z);
            split_store(sV[r][c4 * 4 + 3] * scale, &h.w, &l.w);
            int grow = rowBase + r;
            size_t g = gidx(grow >> 7, c4 >> 3, (c4 >> 1) & 3, grow & 127) + (size_t)(c4 & 1) * 4;
            *reinterpret_cast<ushort4*>(&Ph[g]) = h;
            *reinterpret_cast<ushort4*>(&Pl[g]) = l;
        }
    } else {
        // ---------------- rownorm + zeroing branch ----------------
        const int rb = bid - 512;               // 0..255
        if (t < 128) keys[rb * 128 + t] = 0ULL; // zero 32768 keys total
        if (bid == 512) {
            if (t < 128) diagParts[t] = 0.f;
            if (t < 4) cnt[t] = 0;
        }
        const int wave = t >> 6, lane = t & 63;
#pragma unroll 1
        for (int i = 0; i < 16; ++i) {
            int gr = rb * 64 + wave * 16 + i;    // 0..16383
            const float* V = (gr < N) ? x : y;
            unsigned short* Vh = (gr < N) ? xh : yh;
            unsigned short* Vl = (gr < N) ? xl : yl;
            int row = gr & (N - 1);
            float4 v = *reinterpret_cast<const float4*>(&V[(size_t)row * D + lane * 4]);
            float s = fmaf(v.x, v.x, fmaf(v.y, v.y, fmaf(v.z, v.z, v.w * v.w)));
#pragma unroll
            for (int off = 32; off > 0; off >>= 1) s += __shfl_down(s, off);
            s = __shfl(s, 0);
            float scale = 1.0f / fmaxf(sqrtf(s), 1e-12f);
            ushort4 h, l;
            split_store(v.x * scale, &h.x, &l.x);
            split_store(v.y * scale, &h.y, &l.y);
            split_store(v.z * scale, &h.z, &l.z);
            split_store(v.w * scale, &h.w, &l.w);
            size_t g = gidx(row >> 7, lane >> 3, (lane >> 1) & 3, row & 127) + (size_t)(lane & 1) * 4;
            *reinterpret_cast<ushort4*>(&Vh[g]) = h;
            *reinterpret_cast<ushort4*>(&Vl[g]) = l;
        }
    }
}

// ---------------------------------------------------------------------------
// Kernel 2: sim block 256x256, 8 waves (2Mx4N of 128x64). Per K-tile (K=32):
// slot = {Ah,Al,Bh,Bl} 64 KB; 3 phases (hh/lh/hl), 32 MFMA each; ring-2.
// Staging: wave w stages array (w>>1), panel (w&1); gload j: kq=j>>1, half=j&1.
// ---------------------------------------------------------------------------
__global__ __launch_bounds__(512, 2) void sim_argmax_mfma(
    const unsigned short* __restrict__ Ah, const unsigned short* __restrict__ Al,
    const unsigned short* __restrict__ Bh, const unsigned short* __restrict__ Bl,
    ull* __restrict__ rowKeys, ull* __restrict__ colKeys,
    float* __restrict__ diagParts)
{
    __shared__ s16x8 sS[8192];        // 128 KB ring-2: slot*4096 + arr*1024 + pan*512 + kq*128 + m
    __shared__ ull kbufR[256][4];     // 8 KB
    __shared__ ull kbufC[256][2];     // 4 KB
    __shared__ float sDiag[8];

    const int t = threadIdx.x;
    const int w = t >> 6, lane = t & 63;
    const int wr = w >> 2, wc = w & 3;   // 2x4 wave grid, each 128x64

    // 2D super-tile XCD swizzle: grid 1024 = 32x32 tiles; XCD k owns
    // rowTiles [(k&3)*8,+8) x colTiles [(k>>2)*16,+16); rloc fastest.
    const int bid = blockIdx.x;
    const int xcd = bid & 7, local = bid >> 3;
    const int rowTile = (xcd & 3) * 8 + (local & 7);
    const int colTile = (xcd >> 2) * 16 + (local >> 3);
    const int rowBase = rowTile * 256;
    const int colBase = colTile * 256;

    fp32x4 acc[8][4];
#pragma unroll
    for (int i = 0; i < 8; ++i)
#pragma unroll
        for (int j = 0; j < 4; ++j) acc[i][j] = (fp32x4){0.f, 0.f, 0.f, 0.f};

    // staging role: wave w stages array a = w>>1 (0:Ah 1:Al 2:Bh 3:Bl), panel w&1
    const unsigned short* gptr = ((w >> 1) == 0) ? Ah : ((w >> 1) == 1) ? Al
                               : ((w >> 1) == 2) ? Bh : Bl;
    const int tb = (w < 4) ? rowTile : colTile;
    const size_t gwbase = (size_t)(tb * 2 + (w & 1)) * 4096;   // granules
    const int wLds = (w >> 1) * 1024 + (w & 1) * 512;          // granules in slot

#define STAGE_J(kt, so_, j)                                                               \
    gload16(gptr + (gwbase + (size_t)(kt) * 512 + ((j) >> 1) * 128 + ((j) & 1) * 64 + lane) * 8, \
            (void*)&sS[(so_) + wLds + ((j) >> 1) * 128 + ((j) & 1) * 64])

    // prologue: stage tile 0 into slot 0, drain once
    STAGE_J(0, 0, 0); STAGE_J(0, 0, 1); STAGE_J(0, 0, 2); STAGE_J(0, 0, 3);
    STAGE_J(0, 0, 4); STAGE_J(0, 0, 5); STAGE_J(0, 0, 6); STAGE_J(0, 0, 7);
    asm volatile("s_waitcnt vmcnt(0)" ::: "memory");
    __builtin_amdgcn_s_barrier();
    __builtin_amdgcn_sched_barrier(0);

    // fragment granule bases (within slot)
    const int aH = wr * 512 + (lane >> 4) * 128 + (lane & 15);
    const int aL = 1024 + aH;
    const int bH = 2048 + (wc >> 1) * 512 + (lane >> 4) * 128 + (wc & 1) * 64 + (lane & 15);
    const int bL = 1024 + bH;

#pragma unroll 2
    for (int kt = 0; kt < 8; ++kt) {
        const int so = (kt & 1) * 4096;
        const int nso = ((kt & 1) ^ 1) * 4096;

        // ---------------- Phase A: hh ----------------
        s16x8 ah[8], bh[4];
#pragma unroll
        for (int f = 0; f < 8; ++f) ah[f] = sS[so + aH + f * 16];
#pragma unroll
        for (int f = 0; f < 4; ++f) bh[f] = sS[so + bH + f * 16];
        if (kt < 7) { STAGE_J(kt + 1, nso, 0); STAGE_J(kt + 1, nso, 1);
                      STAGE_J(kt + 1, nso, 2); STAGE_J(kt + 1, nso, 3); }
        __builtin_amdgcn_sched_barrier(0);
        __builtin_amdgcn_s_barrier();
        __builtin_amdgcn_sched_barrier(0);
        __builtin_amdgcn_s_setprio(1);
#pragma unroll
        for (int fm = 0; fm < 8; ++fm)
#pragma unroll
            for (int fn = 0; fn < 4; ++fn)
                acc[fm][fn] = __builtin_amdgcn_mfma_f32_16x16x32_bf16(ah[fm], bh[fn], acc[fm][fn], 0, 0, 0);
        __builtin_amdgcn_s_setprio(0);
        __builtin_amdgcn_s_barrier();

        // ---------------- Phase B: lh ----------------
        {
            s16x8 al[8];
#pragma unroll
            for (int f = 0; f < 8; ++f) al[f] = sS[so + aL + f * 16];
            if (kt < 7) { STAGE_J(kt + 1, nso, 4); STAGE_J(kt + 1, nso, 5);
                          STAGE_J(kt + 1, nso, 6); STAGE_J(kt + 1, nso, 7); }
            __builtin_amdgcn_sched_barrier(0);
            __builtin_amdgcn_s_barrier();
            __builtin_amdgcn_sched_barrier(0);
            __builtin_amdgcn_s_setprio(1);
#pragma unroll
            for (int fm = 0; fm < 8; ++fm)
#pragma unroll
                for (int fn = 0; fn < 4; ++fn)
                    acc[fm][fn] = __builtin_amdgcn_mfma_f32_16x16x32_bf16(al[fm], bh[fn], acc[fm][fn], 0, 0, 0);
            __builtin_amdgcn_s_setprio(0);
            __builtin_amdgcn_s_barrier();
        }

        // ---------------- Phase C: hl ----------------
        {
            s16x8 bl[4];
#pragma unroll
            for (int f = 0; f < 4; ++f) bl[f] = sS[so + bL + f * 16];
            asm volatile("s_waitcnt vmcnt(0)" ::: "memory");   // tile kt+1 landed
            __builtin_amdgcn_sched_barrier(0);
            __builtin_amdgcn_s_barrier();
            __builtin_amdgcn_sched_barrier(0);
            __builtin_amdgcn_s_setprio(1);
#pragma unroll
            for (int fm = 0; fm < 8; ++fm)
#pragma unroll
                for (int fn = 0; fn < 4; ++fn)
                    acc[fm][fn] = __builtin_amdgcn_mfma_f32_16x16x32_bf16(ah[fm], bl[fn], acc[fm][fn], 0, 0, 0);
            __builtin_amdgcn_s_setprio(0);
            __builtin_amdgcn_s_barrier();
        }
    }
#undef STAGE_J

    const int cl = lane & 15, rh = lane >> 4;

    // ---- diagonal (loss) partial ----
    if (rowTile == colTile) {
        float s = 0.f;
        if (wr == (wc >> 1)) {
#pragma unroll
            for (int fm = 0; fm < 8; ++fm) {
                if ((fm >> 2) == (wc & 1)) {
#pragma unroll
                    for (int r = 0; r < 4; ++r)
                        if (cl == rh * 4 + r) s += acc[fm][fm & 3][r];
                }
            }
        }
#pragma unroll
        for (int off = 32; off > 0; off >>= 1) s += __shfl_down(s, off);
        if (lane == 0) sDiag[w] = s;
        __syncthreads();
        if (t == 0) {
            float d = 0.f;
#pragma unroll
            for (int i = 0; i < 8; ++i) d += sDiag[i];
            diagParts[rowTile] = d;
        }
    }

    // ---- row argmax candidates (value-first); C/D: col=lane&15, row=(lane>>4)*4+r
#pragma unroll
    for (int fm = 0; fm < 8; ++fm) {
#pragma unroll
        for (int r = 0; r < 4; ++r) {
            int rowLoc = wr * 128 + fm * 16 + rh * 4 + r;
            float m = fmaxf(fmaxf(acc[fm][0][r], acc[fm][1][r]), fmaxf(acc[fm][2][r], acc[fm][3][r]));
#pragma unroll
            for (int off = 1; off < 16; off <<= 1) m = fmaxf(m, __shfl_xor(m, off));
            unsigned idx = 0xFFFFFFFFu;
#pragma unroll
            for (int fn = 0; fn < 4; ++fn) {
                unsigned gcol = (unsigned)(colBase + wc * 64 + fn * 16 + cl);
                if (acc[fm][fn][r] == m && gcol < idx) idx = gcol;
            }
#pragma unroll
            for (int off = 1; off < 16; off <<= 1) {
                unsigned o = __shfl_xor(idx, off);
                if (o < idx) idx = o;
            }
            if (cl == 0)
                kbufR[rowLoc][wc] = ((ull)f2ord(m) << 32) | (unsigned)(~idx);
        }
    }

    // ---- col argmax candidates ----
#pragma unroll
    for (int fn = 0; fn < 4; ++fn) {
        int colLoc = wc * 64 + fn * 16 + cl;
        float m = -3.4e38f;
#pragma unroll
        for (int fm = 0; fm < 8; ++fm) {
            float m01 = fmaxf(acc[fm][fn][0], acc[fm][fn][1]);
            float m23 = fmaxf(acc[fm][fn][2], acc[fm][fn][3]);
            m = fmaxf(m, fmaxf(m01, m23));
        }
        m = fmaxf(m, __shfl_xor(m, 16));
        m = fmaxf(m, __shfl_xor(m, 32));
        unsigned idx = 0xFFFFFFFFu;
#pragma unroll
        for (int fm = 0; fm < 8; ++fm) {
#pragma unroll
            for (int r = 0; r < 4; ++r) {
                unsigned grow = (unsigned)(rowBase + wr * 128 + fm * 16 + rh * 4 + r);
                if (acc[fm][fn][r] == m && grow < idx) idx = grow;
            }
        }
        {
            unsigned o = __shfl_xor(idx, 16);
            if (o < idx) idx = o;
            o = __shfl_xor(idx, 32);
            if (o < idx) idx = o;
        }
        if (lane < 16)
            kbufC[colLoc][wr] = ((ull)f2ord(m) << 32) | (unsigned)(~idx);
    }

    __syncthreads();

    // ---- one global atomic per row / col ----
    if (t < 256) {
        ull best = umax64(umax64(kbufR[t][0], kbufR[t][1]), umax64(kbufR[t][2], kbufR[t][3]));
        atomicMax(&rowKeys[rowBase + t], best);
    } else {
        int c = t - 256;
        ull best = umax64(kbufC[c][0], kbufC[c][1]);
        atomicMax(&colKeys[colBase + c], best);
    }
}

// ---------------------------------------------------------------------------
// Kernel 3: parallel deterministic counts (int atomics).
// ---------------------------------------------------------------------------
__global__ __launch_bounds__(256) void count_kernel(const ull* __restrict__ keys, int* __restrict__ cnt)
{
    const int t = threadIdx.x;
    const int i = blockIdx.x * 256 + t;
    const int lane = t & 63;
#pragma unroll
    for (int a = 0; a < 4; ++a) {
        int s = ((~(unsigned)keys[a * N + i]) == (unsigned)i);
#pragma unroll
        for (int off = 32; off > 0; off >>= 1) s += __shfl_down(s, off);
        if (lane == 0) atomicAdd(&cnt[a], s);
    }
}

// ---------------------------------------------------------------------------
// Kernel 4: final scalars.
// ---------------------------------------------------------------------------
__global__ __launch_bounds__(64) void final_kernel(
    const float* __restrict__ diagParts, const int* __restrict__ cnt, float* __restrict__ out)
{
    const int lane = threadIdx.x;
    double vx = (double)diagParts[lane];
    double vy = (double)diagParts[64 + lane];
#pragma unroll
    for (int off = 32; off > 0; off >>= 1) {
        vx += __shfl_down(vx, off);
        vy += __shfl_down(vy, off);
    }
    if (lane == 0) {
        float invN = 1.0f / (float)N;
        out[0] = (float)(-0.5 * (vx + vy) / (double)N);
        out[1] = 0.5f * ((float)cnt[1] * invN) + (float)cnt[0] * invN;
        out[2] = 0.5f * ((float)cnt[3] * invN) + (float)cnt[2] * invN;
    }
}

// ---------------------------------------------------------------------------
extern "C" void kernel_launch(void* const* d_in, const int* in_sizes, int n_in,
                              void* d_out, int out_size, void* d_ws, size_t ws_size,
                              hipStream_t stream)
{
    (void)in_sizes; (void)n_in; (void)out_size; (void)ws_size;
    const float* x  = (const float*)d_in[0];
    const float* y  = (const float*)d_in[1];
    const float* W1 = (const float*)d_in[2];
    const float* b1 = (const float*)d_in[3];
    const float* W2 = (const float*)d_in[4];
    const float* b2 = (const float*)d_in[5];
    float* out = (float*)d_out;

    const size_t ND = (size_t)N * D;
    unsigned short* pxh = (unsigned short*)d_ws;   // 8 bf16 planes x 4 MB = 32 MB
    unsigned short* pxl = pxh + ND;
    unsigned short* pyh = pxl + ND;
    unsigned short* pyl = pyh + ND;
    unsigned short* xh  = pyl + ND;
    unsigned short* xl  = xh + ND;
    unsigned short* yh  = xl + ND;
    unsigned short* yl  = yh + ND;
    ull* keys = (ull*)(yl + ND);                   // 256 KB
    ull* rkx = keys + 0 * N;
    ull* ckx = keys + 1 * N;
    ull* rky = keys + 2 * N;
    ull* cky = keys + 3 * N;
    float* diagParts = (float*)(keys + 4 * N);     // 128 floats
    int* cnt = (int*)(diagParts + 128);            // 4 ints

    prep_kernel<<<768, 256, 0, stream>>>(x, y, W1, b1, W2, b2,
                                         pxh, pxl, pyh, pyl, xh, xl, yh, yl,
                                         keys, cnt, diagParts);

    sim_argmax_mfma<<<1024, 512, 0, stream>>>(pxh, pxl, yh, yl, rkx, ckx, diagParts);
    sim_argmax_mfma<<<1024, 512, 0, stream>>>(pyh, pyl, xh, xl, rky, cky, diagParts + 64);

    count_kernel<<<32, 256, 0, stream>>>(keys, cnt);
    final_kernel<<<1, 64, 0, stream>>>(diagParts, cnt, out);
}